// Round 6
// baseline (682.777 us; speedup 1.0000x reference)
//
#include <hip/hip_runtime.h>

#define B_ 64
#define T_ 512
#define D_ 1024
#define C_ 32
#define NEG_INF (-1e30f)

__device__ __forceinline__ float bcast0(float v) {
  return __uint_as_float(__builtin_amdgcn_readfirstlane(__float_as_uint(v)));
}
__device__ __forceinline__ float bperm_f(int byteaddr, float v) {
  return __int_as_float(__builtin_amdgcn_ds_bpermute(byteaddr, __float_as_int(v)));
}
__device__ __forceinline__ int bperm_i(int byteaddr, int v) {
  return __builtin_amdgcn_ds_bpermute(byteaddr, v);
}

// ---------------- logits = vectors @ W^T + b (f32, sequential-k fma chain) ----------------
// grid 512, block 256 (2 blocks/CU -> 2 waves/SIMD TLP). Block tile: 64 rows x 32 cols.
// Thread: 2 rows (stride 32) x 4 cols (stride 8). Per-output arithmetic is the
// SAME sequential-k fmaf chain as the R5 passing kernel -> bit-identical logits.
__global__ __launch_bounds__(256) void k_logits(const float* __restrict__ vec,
                                                const float* __restrict__ W,
                                                const float* __restrict__ bias,
                                                float* __restrict__ out) {
  const int tid = threadIdx.x;
  const int cg = tid & 7;   // col base 0..7  (cols cg + 8*cc)
  const int rg = tid >> 3;  // 0..31          (rows r0 + rg + 32*rr)
  const int r0 = blockIdx.x * 64;
  float acc[2][4];
#pragma unroll
  for (int a = 0; a < 2; ++a)
#pragma unroll
    for (int bb = 0; bb < 4; ++bb) acc[a][bb] = 0.f;
  const float* vb = vec + (size_t)(r0 + rg) * D_;
  const float* wb = W + (size_t)cg * D_;
#pragma unroll 4
  for (int k = 0; k < D_; k += 4) {
    float4 v[2], w[4];
#pragma unroll
    for (int rr = 0; rr < 2; ++rr) v[rr] = *(const float4*)(vb + (size_t)rr * 32 * D_ + k);
#pragma unroll
    for (int cc = 0; cc < 4; ++cc) w[cc] = *(const float4*)(wb + (size_t)cc * 8 * D_ + k);
#pragma unroll
    for (int rr = 0; rr < 2; ++rr)
#pragma unroll
      for (int cc = 0; cc < 4; ++cc) {
        acc[rr][cc] = fmaf(v[rr].x, w[cc].x, acc[rr][cc]);
        acc[rr][cc] = fmaf(v[rr].y, w[cc].y, acc[rr][cc]);
        acc[rr][cc] = fmaf(v[rr].z, w[cc].z, acc[rr][cc]);
        acc[rr][cc] = fmaf(v[rr].w, w[cc].w, acc[rr][cc]);
      }
  }
#pragma unroll
  for (int rr = 0; rr < 2; ++rr) {
    const size_t row = (size_t)(r0 + rg + rr * 32);
#pragma unroll
    for (int cc = 0; cc < 4; ++cc) {
      const int c = cg + cc * 8;
      out[row * C_ + c] = acc[rr][cc] + bias[c];  // b32 store: out base only 4B-aligned
    }
  }
}

// ---------------- CRF: forward(+score) and Viterbi(+backtrace) ----------------
// grid 128 x 64 threads (one wave64 per block). State broadcast via ds_bpermute
// (register-resident delta/alpha, no LDS round-trip, no exec-mask dance).
// blocks 0..63: forward logsumexp + logZ + gold score (f32).
// blocks 64..127: f32 Viterbi, bit-replicating np-f32 (elementwise f32 adds;
// max/argmax in any tree order is exact; first-index ties via contiguous-pair
// tournament + index-guarded cross-half merge).
__global__ __launch_bounds__(64) void k_crf(const float* __restrict__ lg,
                                            const int* __restrict__ mask,
                                            const int* __restrict__ tgt,
                                            const float* __restrict__ trans,
                                            const float* __restrict__ st,
                                            const float* __restrict__ et,
                                            float* __restrict__ wsp,
                                            float* __restrict__ tags_out,
                                            float* __restrict__ path_out) {
  __shared__ unsigned char bp[(T_ - 1) * C_];
  __shared__ unsigned char tagb[T_];
  __shared__ unsigned char c8[64 * C_];
  __shared__ int btag[64];

  const int tid = threadIdx.x;
  const int b = blockIdx.x & 63;
  const int role = blockIdx.x >> 6;
  const int j = tid & 31;
  const int h = tid >> 5;  // half: source range [16h, 16h+16)
  const float* L = lg + (size_t)b * T_ * C_;
  const int* mk = mask + b * T_;

  // bpermute byte addresses (precomputed, loop-invariant VGPRs)
  int baddr[16];
#pragma unroll
  for (int i = 0; i < 16; ++i) baddr[i] = (h * 16 + i) * 4;
  const int xaddr = (tid ^ 32) * 4;

  if (role == 0) {
    // ================= forward + score =================
    float ET[16];
#pragma unroll
    for (int i = 0; i < 16; ++i) ET[i] = __expf(trans[(h * 16 + i) * C_ + j]);
    float alpha = st[j] + L[j];  // all 64 lanes hold alpha_{j}
    // distance-2 rotating prefetch of L and mask
    float lnx1 = L[C_ + j], lnx2 = L[2 * C_ + j];
    int mnx1 = mk[1], mnx2 = mk[2];
    for (int t = 1; t < T_; ++t) {
      const float lc = lnx1;
      const int mc = mnx1;
      lnx1 = lnx2; mnx1 = mnx2;
      const int t2 = (t + 2 < T_) ? t + 2 : T_ - 1;
      lnx2 = L[t2 * C_ + j]; mnx2 = mk[t2];
      const float mhat = bcast0(alpha);  // spread bounded -> no overflow
      const float av = __expf(alpha - mhat);
      float p[16];
#pragma unroll
      for (int i = 0; i < 16; ++i) p[i] = bperm_f(baddr[i], av);
      float s0 = p[0] * ET[0], s1 = p[1] * ET[1], s2 = p[2] * ET[2], s3 = p[3] * ET[3];
      s0 = fmaf(p[4], ET[4], s0);   s1 = fmaf(p[5], ET[5], s1);
      s2 = fmaf(p[6], ET[6], s2);   s3 = fmaf(p[7], ET[7], s3);
      s0 = fmaf(p[8], ET[8], s0);   s1 = fmaf(p[9], ET[9], s1);
      s2 = fmaf(p[10], ET[10], s2); s3 = fmaf(p[11], ET[11], s3);
      s0 = fmaf(p[12], ET[12], s0); s1 = fmaf(p[13], ET[13], s1);
      s2 = fmaf(p[14], ET[14], s2); s3 = fmaf(p[15], ET[15], s3);
      float sp = (s0 + s1) + (s2 + s3);
      sp += bperm_f(xaddr, sp);  // combine halves
      const float anew = mhat + __logf(sp) + lc;
      if (mc > 0) alpha = anew;  // uniform across halves
    }
    float val = (tid < 32) ? (alpha + et[j]) : NEG_INF;
    float mm = val;
#pragma unroll
    for (int d = 32; d; d >>= 1) mm = fmaxf(mm, __shfl_xor(mm, d));
    float ee = __expf(val - mm);
#pragma unroll
    for (int d = 32; d; d >>= 1) ee += __shfl_xor(ee, d);
    const float logZ = mm + __logf(ee);
    float sc = 0.f, msf = 0.f;
#pragma unroll
    for (int kk = 0; kk < 8; ++kk) {
      const int t = tid + kk * 64;
      const float mf = (float)mk[t];
      const int tg = tgt[b * T_ + t];
      msf += mf;
      float contrib = 0.f;
      if (t >= 1) contrib += trans[tgt[b * T_ + t - 1] * C_ + tg];
      if (t <= T_ - 2) contrib += L[t * C_ + tg];
      sc = fmaf(mf, contrib, sc);
    }
#pragma unroll
    for (int d = 32; d; d >>= 1) { sc += __shfl_xor(sc, d); msf += __shfl_xor(msf, d); }
    if (tid == 0) {
      int last_idx = (int)msf - 1;
      if (last_idx < 0) last_idx = 0;
      const int lt = tgt[b * T_ + last_idx];
      float s = sc + st[tgt[b * T_]] + et[lt];
      s = fmaf((float)mk[T_ - 1], L[(T_ - 1) * C_ + lt], s);
      wsp[b] = logZ;
      wsp[64 + b] = s;
      wsp[128 + b] = msf;
    }
  } else {
    // ================= Viterbi (f32, np-f32-bit-replicating) =================
    float TT[16];
#pragma unroll
    for (int i = 0; i < 16; ++i) TT[i] = trans[(h * 16 + i) * C_ + j];
    float dj = st[j] + L[j];  // all 64 lanes hold delta_{j}
    float lnx1 = L[C_ + j], lnx2 = L[2 * C_ + j];
    int mnx1 = mk[1], mnx2 = mk[2];
    unsigned bpaddr0 = (unsigned)(size_t)0;  // (unused; bp indexed directly)
    (void)bpaddr0;
    for (int t = 1; t < T_; ++t) {
      const float lc = lnx1;
      const int mc = mnx1;
      lnx1 = lnx2; mnx1 = mnx2;
      const int t2 = (t + 2 < T_) ? t + 2 : T_ - 1;
      lnx2 = L[t2 * C_ + j]; mnx2 = mk[t2];
      // distribute delta via bpermute; plain f32 add (matches np delta + trans)
      float c[16];
#pragma unroll
      for (int i = 0; i < 16; ++i) c[i] = bperm_f(baddr[i], dj) + TT[i];
      // contiguous-pair tournament: left subtree indices always < right ->
      // strict '>' (right wins only if greater) == np.argmax first-index.
      float v[8]; int x[8];
#pragma unroll
      for (int i = 0; i < 8; ++i) {
        const bool g = c[2 * i + 1] > c[2 * i];
        v[i] = g ? c[2 * i + 1] : c[2 * i];
        x[i] = g ? 2 * i + 1 : 2 * i;
      }
#pragma unroll
      for (int i = 0; i < 4; ++i) {
        const bool g = v[2 * i + 1] > v[2 * i];
        v[i] = g ? v[2 * i + 1] : v[2 * i];
        x[i] = g ? x[2 * i + 1] : x[2 * i];
      }
#pragma unroll
      for (int i = 0; i < 2; ++i) {
        const bool g = v[2 * i + 1] > v[2 * i];
        v[i] = g ? v[2 * i + 1] : v[2 * i];
        x[i] = g ? x[2 * i + 1] : x[2 * i];
      }
      float v0 = (v[1] > v[0]) ? v[1] : v[0];
      int big = h * 16 + ((v[1] > v[0]) ? x[1] : x[0]);
      // cross-half merge (index-guarded: ties -> lower global index)
      const float ov = bperm_f(xaddr, v0);
      const int oi = bperm_i(xaddr, big);
      if (ov > v0 || (ov == v0 && oi < big)) { v0 = ov; big = oi; }
      int bpv = j;
      if (mc > 0) { dj = v0 + lc; bpv = big; }  // f32 add: matches np best+lt
      bp[(t - 1) * C_ + j] = (unsigned char)bpv;  // lanes j, j+32: same addr, same data
    }
    // final argmax (first-index tie-break) + path score — f32 elementwise
    float fv = (tid < 32) ? (dj + et[j]) : NEG_INF;
    int fi = (tid < 32) ? j : 64;
#pragma unroll
    for (int d = 32; d; d >>= 1) {
      const float ovv = __shfl_xor(fv, d);
      const int oii = __shfl_xor(fi, d);
      if (ovv > fv || (ovv == fv && oii < fi)) { fv = ovv; fi = oii; }
    }
    const int last_tag = fi;
    if (tid == 0) path_out[b] = fv;
    // ---- backtrace: 8-step jump maps (validated R3==R4) ----
    int cur[32];
#pragma unroll
    for (int e = 0; e < 32; ++e) cur[e] = (tid + 64 * e) & 31;
#pragma unroll
    for (int s = 0; s < 8; ++s) {
#pragma unroll
      for (int e = 0; e < 32; ++e) {
        const int m = (tid + 64 * e) >> 5;
        const int r = 8 * m + 7 - s;
        if (r <= T_ - 2) cur[e] = bp[r * C_ + cur[e]];
      }
    }
#pragma unroll
    for (int e = 0; e < 32; ++e) c8[tid + 64 * e] = (unsigned char)cur[e];
    if (tid == 0) {
      int cc = last_tag;
      tagb[T_ - 1] = (unsigned char)cc;
      for (int m = 63; m >= 0; --m) { cc = c8[m * C_ + cc]; btag[m] = cc; }  // btag[m]=tag_{8m}
    }
    {
      const int m = tid;
      const int rhi = (m == 63) ? (T_ - 2) : (8 * m + 7);
      int cc = (m == 63) ? last_tag : btag[m + 1];
#pragma unroll
      for (int s = 0; s < 7; ++s) {
        const int r = rhi - s;
        if (r >= 8 * m + 1) { cc = bp[r * C_ + cc]; tagb[r] = (unsigned char)cc; }
      }
      tagb[8 * m] = (unsigned char)btag[m];
    }
#pragma unroll
    for (int kk = 0; kk < 8; ++kk) {
      const int t = tid + kk * 64;
      tags_out[b * T_ + t] = (float)tagb[t];
    }
  }
}

// ---------------- loss reduction ----------------
__global__ __launch_bounds__(64) void k_loss(const float* __restrict__ wsp, float* __restrict__ out0) {
  const int tid = threadIdx.x;
  float d = wsp[64 + tid] - wsp[tid];
  float m = wsp[128 + tid];
#pragma unroll
  for (int s = 32; s; s >>= 1) { d += __shfl_xor(d, s); m += __shfl_xor(m, s); }
  if (tid == 0) out0[0] = -d / m;
}

extern "C" void kernel_launch(void* const* d_in, const int* in_sizes, int n_in,
                              void* d_out, int out_size, void* d_ws, size_t ws_size,
                              hipStream_t stream) {
  (void)in_sizes; (void)n_in; (void)out_size; (void)ws_size;
  const float* vec  = (const float*)d_in[0];
  const int* mask   = (const int*)d_in[1];
  const int* tgt    = (const int*)d_in[2];
  const float* W    = (const float*)d_in[3];
  const float* bias = (const float*)d_in[4];
  const float* tr   = (const float*)d_in[5];
  const float* st   = (const float*)d_in[6];
  const float* et   = (const float*)d_in[7];
  float* out = (float*)d_out;
  float* logits = out + 1;
  float* tags = out + 1 + (size_t)B_ * T_ * C_;
  float* path = tags + (size_t)B_ * T_;
  float* wsp = (float*)d_ws;  // [0,64): logZ  [64,128): score  [128,192): mask-sum

  hipLaunchKernelGGL(k_logits, dim3(512), dim3(256), 0, stream, vec, W, bias, logits);
  hipLaunchKernelGGL(k_crf, dim3(128), dim3(64), 0, stream, logits, mask, tgt, tr, st, et, wsp, tags, path);
  hipLaunchKernelGGL(k_loss, dim3(1), dim3(64), 0, stream, wsp, out);
}